// Round 1
// baseline (322.293 us; speedup 1.0000x reference)
//
#include <hip/hip_runtime.h>

typedef unsigned short u16;
typedef __attribute__((ext_vector_type(8))) short short8;   // 8 bf16 (4 VGPRs) - MFMA A/B frag
typedef __attribute__((ext_vector_type(4))) float f4;       // MFMA C/D frag
typedef __attribute__((ext_vector_type(8))) unsigned short us8;

// ---------- helpers ----------
__device__ __forceinline__ u16 f2bf(float f) {              // RNE fp32 -> bf16
    unsigned u = __float_as_uint(f);
    u += 0x7FFFu + ((u >> 16) & 1u);
    return (u16)(u >> 16);
}
__device__ __forceinline__ float bf2f(u16 h) {
    return __uint_as_float(((unsigned)h) << 16);
}

#define GLD16(gp, lp) __builtin_amdgcn_global_load_lds( \
    (const __attribute__((address_space(1))) void*)(gp), \
    (__attribute__((address_space(3))) void*)(lp), 16, 0, 0)

// s = (d_head^0.5)^(-0.25) = 8^(-0.25)
#define SCALE_S 0.594603557501360533f

// ---------- fp32 -> bf16 (8 elems/thread) ----------
__global__ __launch_bounds__(256) void convert_f32_bf16(const float* __restrict__ in,
                                                        u16* __restrict__ out) {
    const size_t i = (size_t)blockIdx.x * 256 + threadIdx.x;
    const float4* p = (const float4*)in + i * 2;
    float4 a = p[0], b = p[1];
    us8 r;
    r[0] = f2bf(a.x); r[1] = f2bf(a.y); r[2] = f2bf(a.z); r[3] = f2bf(a.w);
    r[4] = f2bf(b.x); r[5] = f2bf(b.y); r[6] = f2bf(b.z); r[7] = f2bf(b.w);
    *(us8*)(out + i * 8) = r;
}

// ---------- transpose + convert x3: out[n][k] = bf16(W[k][n]), 1024x1024 ----------
__global__ __launch_bounds__(256) void transpose_convert3(
    const float* __restrict__ Wq, const float* __restrict__ Wv, const float* __restrict__ Wo,
    u16* __restrict__ WqvT, u16* __restrict__ WoT) {
    const float* W; u16* out;
    if (blockIdx.z == 0)      { W = Wq; out = WqvT; }
    else if (blockIdx.z == 1) { W = Wv; out = WqvT + 1024 * 1024; }
    else                      { W = Wo; out = WoT; }
    __shared__ float tile[32][33];
    const int tx = threadIdx.x, ty = threadIdx.y;   // 32 x 8
    const int x = blockIdx.x * 32 + tx;
#pragma unroll
    for (int i = 0; i < 4; ++i) {
        const int y = blockIdx.y * 32 + ty + i * 8;
        tile[ty + i * 8][tx] = W[(size_t)y * 1024 + x];
    }
    __syncthreads();
#pragma unroll
    for (int i = 0; i < 4; ++i) {
        const int yo = blockIdx.x * 32 + ty + i * 8;  // out row (= W col)
        const int xo = blockIdx.y * 32 + tx;          // out col (= W row)
        out[(size_t)yo * 1024 + xo] = f2bf(tile[tx][ty + i * 8]);
    }
}

__global__ void concat_bias(const float* __restrict__ bq, const float* __restrict__ bv,
                            float* __restrict__ bqv) {
    const int i = blockIdx.x * 256 + threadIdx.x;   // 0..2047
    bqv[i] = (i < 1024) ? bq[i] : bv[i - 1024];
}

// ============================================================================
// 256x256 8-phase GEMM core (T2 swizzle + T3/T4 counted-vmcnt + T5 setprio).
// 512 threads = 8 waves (2M x 4N), per-wave out 128x64, BK=64, LDS 128 KiB.
// Ledger (per-wave GLD16 counts, 2 per half-tile):
//   prologue: stage B(k0),A(k0),B(k1) [12 loads]; vmcnt(4) -> k0 fully landed.
//   kt body:  p0 stages A0(kt+1), p1 A1(kt+1), p2 B0(kt+2), p3 B1(kt+2);
//             single vmcnt(4) before p3's end barrier -> A(kt+1)+B(kt+1) landed,
//             only B(kt+2) (4 loads) in flight. Never 0 in the loop.
//   B-frags ds_read once per K-tile at p0 and held in regs -> B slots free from p1.
//   A rows [32p,32p+32) read at phase p -> A(kt) slots never overwritten during kt.
//   Every slot overwrite is >=1 barrier after its last read (reads drain via
//   compiler lgkmcnt before each phase's MFMA, which precedes the end barrier).
// Last 2 K-tiles peeled after a single vmcnt(0) drain.
// ============================================================================
#define BAR8() do { asm volatile("" ::: "memory"); __builtin_amdgcn_s_barrier(); \
                    asm volatile("" ::: "memory"); } while (0)
#define WAITV(n) asm volatile("s_waitcnt vmcnt(" #n ")" ::: "memory")

// src already includes (row0)*1024 + swizzled col; half advances 128 rows, round +64 rows
#define STG(dst, src, dbuf, half, kt) do { \
    const u16* s_ = (src) + (size_t)(half) * 128 * 1024 + (size_t)(kt) * 64; \
    u16* d_ = &dst[dbuf][half][ldst]; \
    GLD16(s_, d_); \
    GLD16(s_ + (size_t)64 * 1024, d_ + 64 * 64); \
} while (0)

#define LOADB() do { \
    _Pragma("unroll") for (int j_ = 0; j_ < 4; ++j_) \
    _Pragma("unroll") for (int kk_ = 0; kk_ < 2; ++kk_) \
        bf[j_][kk_] = *(const short8*)&Bb[(brow + j_ * 16 + lrow) * 64 + (kg0 ^ (kk_ << 5))]; \
} while (0)

#define PHASE(p, STAGE_STMT, TAIL_WAIT) do { \
    short8 af[2][2]; \
    _Pragma("unroll") for (int i2_ = 0; i2_ < 2; ++i2_) \
    _Pragma("unroll") for (int kk_ = 0; kk_ < 2; ++kk_) \
        af[i2_][kk_] = *(const short8*)&Ab[(((p) * 2 + i2_) * 16 + lrow) * 64 + (kg0 ^ (kk_ << 5))]; \
    STAGE_STMT; \
    BAR8(); \
    __builtin_amdgcn_s_setprio(1); \
    _Pragma("unroll") for (int kk_ = 0; kk_ < 2; ++kk_) \
    _Pragma("unroll") for (int i2_ = 0; i2_ < 2; ++i2_) \
    _Pragma("unroll") for (int j_ = 0; j_ < 4; ++j_) \
        acc[(p) * 2 + i2_][j_] = __builtin_amdgcn_mfma_f32_16x16x32_bf16( \
            af[i2_][kk_], bf[j_][kk_], acc[(p) * 2 + i2_][j_], 0, 0, 0); \
    __builtin_amdgcn_s_setprio(0); \
    TAIL_WAIT; \
    BAR8(); \
} while (0)

// ---------- GEMM1: [x] @ [WqT;WvT]^T + bias, fused first-softmax epilogue ----------
__global__ __launch_bounds__(512, 2) void gemm_qv(
    const u16* __restrict__ A, const u16* __restrict__ BT,
    const float* __restrict__ bias,
    u16* __restrict__ qsOut, u16* __restrict__ vOut)
{
    __shared__ u16 As[2][2][128 * 64];
    __shared__ u16 Bs[2][2][128 * 64];
    const int t = threadIdx.x;
    const int l = t & 63, w = t >> 6;
    const int quad = l >> 4, lrow = l & 15;
    const int wrow = w >> 2, wcol = w & 3;
    const int bhalf = wcol >> 1, brow = (wcol & 1) * 64;

    int bx, by;
    {
        const int id = blockIdx.x + (int)gridDim.x * blockIdx.y;
        const int xcd = id & 7, j = id >> 3;
        const int xs = (int)gridDim.x >> 3;
        bx = xcd * xs + (j % xs);
        by = j / xs;
    }
    const int m0 = bx * 256, n0 = by * 256;

    const int lr0 = t >> 3;                      // row within half, round 0 (0..63)
    const int cg = ((t & 7) ^ (lr0 & 7)) * 8;    // swizzled k-granule (same both rounds: 64%8==0)
    const int ldst = lr0 * 64 + (t & 7) * 8;     // LDS dst (u16) = uniform + lane*8 u16 = lane*16B
    const u16* aS = A  + (size_t)(m0 + lr0) * 1024 + cg;
    const u16* bS = BT + (size_t)(n0 + lr0) * 1024 + cg;

    const int kg0 = (quad ^ (lrow & 7)) << 3;
    f4 acc[8][4] = {};

    // prologue: k0 full + B(k1)
    STG(Bs, bS, 0, 0, 0); STG(Bs, bS, 0, 1, 0);
    STG(As, aS, 0, 0, 0); STG(As, aS, 0, 1, 0);
    STG(Bs, bS, 1, 0, 1); STG(Bs, bS, 1, 1, 1);
    WAITV(4);
    BAR8();

    for (int kt = 0; kt < 14; ++kt) {
        const int d = kt & 1;
        const u16* Ab = As[d][wrow];
        const u16* Bb = Bs[d][bhalf];
        short8 bf[4][2];
        LOADB();
        PHASE(0, STG(As, aS, d ^ 1, 0, kt + 1), (void)0);
        PHASE(1, STG(As, aS, d ^ 1, 1, kt + 1), (void)0);
        PHASE(2, STG(Bs, bS, d, 0, kt + 2), (void)0);
        PHASE(3, STG(Bs, bS, d, 1, kt + 2), WAITV(4));
    }
    // peel kt=14,15: only A(15) remains unstaged
    STG(As, aS, 1, 0, 15); STG(As, aS, 1, 1, 15);
    WAITV(0);
    BAR8();
#pragma unroll
    for (int kt = 14; kt < 16; ++kt) {
        const int d = kt & 1;
        const u16* Ab = As[d][wrow];
        const u16* Bb = Bs[d][bhalf];
        short8 bf[4][2];
        LOADB();
#pragma unroll
        for (int p = 0; p < 4; ++p) {
            short8 af[2][2];
#pragma unroll
            for (int i2 = 0; i2 < 2; ++i2)
#pragma unroll
                for (int kk = 0; kk < 2; ++kk)
                    af[i2][kk] = *(const short8*)&Ab[((p * 2 + i2) * 16 + lrow) * 64 + (kg0 ^ (kk << 5))];
#pragma unroll
            for (int kk = 0; kk < 2; ++kk)
#pragma unroll
                for (int i2 = 0; i2 < 2; ++i2)
#pragma unroll
                    for (int j = 0; j < 4; ++j)
                        acc[p * 2 + i2][j] = __builtin_amdgcn_mfma_f32_16x16x32_bf16(
                            af[i2][kk], bf[j][kk], acc[p * 2 + i2][j], 0, 0, 0);
        }
    }

    // epilogue: wave's 64-col span = one head (n0, wcol*64 both 64-aligned)
    const int colb = n0 + wcol * 64 + lrow;
    const float b0 = bias[colb], b1 = bias[colb + 16], b2 = bias[colb + 32], b3 = bias[colb + 48];
    const bool isQ = n0 < 1024;                 // block-uniform (256-wide tiles)
#pragma unroll
    for (int i = 0; i < 8; ++i) {
        const int rbase = m0 + wrow * 128 + i * 16 + quad * 4;
#pragma unroll
        for (int r = 0; r < 4; ++r) {
            float v0 = acc[i][0][r] + b0;
            float v1 = acc[i][1][r] + b1;
            float v2 = acc[i][2][r] + b2;
            float v3 = acc[i][3][r] + b3;
            if (isQ) {
                float m = fmaxf(fmaxf(v0, v1), fmaxf(v2, v3));
                m = fmaxf(m, __shfl_xor(m, 1));
                m = fmaxf(m, __shfl_xor(m, 2));
                m = fmaxf(m, __shfl_xor(m, 4));
                m = fmaxf(m, __shfl_xor(m, 8));
                float e0 = __expf(v0 - m), e1 = __expf(v1 - m);
                float e2 = __expf(v2 - m), e3 = __expf(v3 - m);
                float sm = e0 + e1 + e2 + e3;
                sm += __shfl_xor(sm, 1);
                sm += __shfl_xor(sm, 2);
                sm += __shfl_xor(sm, 4);
                sm += __shfl_xor(sm, 8);
                const float inv = SCALE_S / sm;
                u16* qp = qsOut + (size_t)(rbase + r) * 1024 + colb;
                qp[0]  = f2bf(e0 * inv);
                qp[16] = f2bf(e1 * inv);
                qp[32] = f2bf(e2 * inv);
                qp[48] = f2bf(e3 * inv);
            } else {
                u16* vp = vOut + (size_t)(rbase + r) * 1024 + (colb - 1024);
                vp[0]  = f2bf(v0);
                vp[16] = f2bf(v1);
                vp[32] = f2bf(v2);
                vp[48] = f2bf(v3);
            }
        }
    }
}

// ---------- GEMM3: out[z] = qs[z] @ WopT[z]^T + bo (fp32 store) ----------
__global__ __launch_bounds__(512, 2) void gemm_out(
    const u16* __restrict__ A, const u16* __restrict__ BT,
    const float* __restrict__ bias, float* __restrict__ C)
{
    __shared__ u16 As[2][2][128 * 64];
    __shared__ u16 Bs[2][2][128 * 64];
    const int t = threadIdx.x;
    const int l = t & 63, w = t >> 6;
    const int quad = l >> 4, lrow = l & 15;
    const int wrow = w >> 2, wcol = w & 3;
    const int bhalf = wcol >> 1, brow = (wcol & 1) * 64;
    const int z = blockIdx.z;
    A  += (size_t)z * (4096 * 1024);
    BT += (size_t)z * (1024 * 1024);
    C  += (size_t)z * (4096 * 1024);

    int bx, by;
    {
        const int id = blockIdx.x + (int)gridDim.x * blockIdx.y;
        const int xcd = id & 7, j = id >> 3;
        const int xs = (int)gridDim.x >> 3;    // 2
        bx = xcd * xs + (j % xs);
        by = j / xs;
    }
    const int m0 = bx * 256, n0 = by * 256;

    const int lr0 = t >> 3;
    const int cg = ((t & 7) ^ (lr0 & 7)) * 8;
    const int ldst = lr0 * 64 + (t & 7) * 8;
    const u16* aS = A  + (size_t)(m0 + lr0) * 1024 + cg;
    const u16* bS = BT + (size_t)(n0 + lr0) * 1024 + cg;

    const int kg0 = (quad ^ (lrow & 7)) << 3;
    f4 acc[8][4] = {};

    STG(Bs, bS, 0, 0, 0); STG(Bs, bS, 0, 1, 0);
    STG(As, aS, 0, 0, 0); STG(As, aS, 0, 1, 0);
    STG(Bs, bS, 1, 0, 1); STG(Bs, bS, 1, 1, 1);
    WAITV(4);
    BAR8();

    for (int kt = 0; kt < 14; ++kt) {
        const int d = kt & 1;
        const u16* Ab = As[d][wrow];
        const u16* Bb = Bs[d][bhalf];
        short8 bf[4][2];
        LOADB();
        PHASE(0, STG(As, aS, d ^ 1, 0, kt + 1), (void)0);
        PHASE(1, STG(As, aS, d ^ 1, 1, kt + 1), (void)0);
        PHASE(2, STG(Bs, bS, d, 0, kt + 2), (void)0);
        PHASE(3, STG(Bs, bS, d, 1, kt + 2), WAITV(4));
    }
    STG(As, aS, 1, 0, 15); STG(As, aS, 1, 1, 15);
    WAITV(0);
    BAR8();
#pragma unroll
    for (int kt = 14; kt < 16; ++kt) {
        const int d = kt & 1;
        const u16* Ab = As[d][wrow];
        const u16* Bb = Bs[d][bhalf];
        short8 bf[4][2];
        LOADB();
#pragma unroll
        for (int p = 0; p < 4; ++p) {
            short8 af[2][2];
#pragma unroll
            for (int i2 = 0; i2 < 2; ++i2)
#pragma unroll
                for (int kk = 0; kk < 2; ++kk)
                    af[i2][kk] = *(const short8*)&Ab[((p * 2 + i2) * 16 + lrow) * 64 + (kg0 ^ (kk << 5))];
#pragma unroll
            for (int kk = 0; kk < 2; ++kk)
#pragma unroll
                for (int i2 = 0; i2 < 2; ++i2)
#pragma unroll
                    for (int j = 0; j < 4; ++j)
                        acc[p * 2 + i2][j] = __builtin_amdgcn_mfma_f32_16x16x32_bf16(
                            af[i2][kk], bf[j][kk], acc[p * 2 + i2][j], 0, 0, 0);
        }
    }

    const int colb = n0 + wcol * 64 + lrow;
    const float b0 = bias[colb], b1 = bias[colb + 16], b2 = bias[colb + 32], b3 = bias[colb + 48];
#pragma unroll
    for (int i = 0; i < 8; ++i) {
        const int rbase = m0 + wrow * 128 + i * 16 + quad * 4;
#pragma unroll
        for (int r = 0; r < 4; ++r) {
            float* cp = C + (size_t)(rbase + r) * 1024 + colb;
            cp[0]  = acc[i][0][r] + b0;
            cp[16] = acc[i][1][r] + b1;
            cp[32] = acc[i][2][r] + b2;
            cp[48] = acc[i][3][r] + b3;
        }
    }
}

// ---------- ctx partials via MFMA: Mpart[split][g][d][e] = sum_n exp(qs[n,d]) * v[n,e] ----
__global__ __launch_bounds__(256) void ctx_mfma(
    const u16* __restrict__ qs, const u16* __restrict__ vb,
    float* __restrict__ Mpart, float* __restrict__ Zpart)
{
    __shared__ __align__(16) u16 Et[2][64 * 64];
    __shared__ __align__(16) u16 Vt[2][64 * 64];
    const int t = threadIdx.x;
    const int w = t >> 6, l = t & 63;
    const int quad = l >> 4, lrow = l & 15;
    const int g = blockIdx.x;          // b = g>>4, h = g&15
    const int split = blockIdx.y;      // 0..15
    const int b = g >> 4, h = g & 15;

    const int n0 = (l & 31) * 2;       // rows n0, n0+1 within slab
    const int d0 = w * 16 + (l >> 5) * 8;
    const u16* qp = qs + ((size_t)b * 4096 + (size_t)split * 256 + n0) * 1024 + h * 64 + d0;
    const u16* vp = vb + ((size_t)b * 4096 + (size_t)split * 256 + n0) * 1024 + h * 64 + d0;

    f4 acc[4] = {};
    float zacc[8] = {};

    us8 q8a = *(const us8*)qp;
    us8 q8b = *(const us8*)(qp + 1024);
    us8 v8a = *(const us8*)vp;
    us8 v8b = *(const us8*)(vp + 1024);

    for (int slab = 0; slab < 4; ++slab) {
        unsigned epk[8], vpk[8];
#pragma unroll
        for (int j = 0; j < 8; ++j) {
            float ea = __expf(bf2f((u16)q8a[j]));
            float eb = __expf(bf2f((u16)q8b[j]));
            zacc[j] += ea + eb;
            epk[j] = (unsigned)f2bf(ea) | ((unsigned)f2bf(eb) << 16);
            vpk[j] = (unsigned)(u16)v8a[j] | ((unsigned)(u16)v8b[j] << 16);
        }
        if (slab < 3) {                // prefetch next slab (overlaps sync+MFMA below)
            qp += 64 * 1024; vp += 64 * 1024;
            q8a = *(const us8*)qp;  q8b = *(const us8*)(qp + 1024);
            v8a = *(const us8*)vp;  v8b = *(const us8*)(vp + 1024);
        }
        u16* et = Et[slab & 1];
        u16* vt = Vt[slab & 1];
#pragma unroll
        for (int j = 0; j < 8; ++j) {
            const int d = d0 + j;
            const int off = d * 64 + (((n0 >> 3) ^ (d & 7)) << 3) + (n0 & 7);
            *(unsigned*)&et[off] = epk[j];
            *(unsigned*)&vt[off] = vpk[j];
        }
        __syncthreads();
#pragma unroll
        for (int kk = 0; kk < 2; ++kk) {
            const int blk = ((kk * 4 + quad) ^ (lrow & 7)) << 3;
            short8 a = *(const short8*)&et[(w * 16 + lrow) * 64 + blk];
#pragma unroll
            for (int j = 0; j < 4; ++j) {
                short8 bfr = *(const short8*)&vt[(j * 16 + lrow) * 64 + blk];
                acc[j] = __builtin_amdgcn_mfma_f32_16x16x32_bf16(a, bfr, acc[j], 0, 0, 0);
            }
        }
    }

    // Z: butterfly within each 32-lane half (all lanes of a half share d0-range)
#pragma unroll
    for (int j = 0; j < 8; ++j) {
        zacc[j] += __shfl_xor(zacc[j], 1);
        zacc[j] += __shfl_xor(zacc[j], 2);
        zacc[j] += __shfl_xor(zacc[j], 4);
        zacc[j] += __shfl_xor(zacc[j], 8);
        zacc[j] += __shfl_xor(zacc[j], 16);
    }
    if ((l & 31) == 0) {
        float* zp = Zpart + ((size_t)split * 64 + g) * 64 + d0;
#pragma unroll
        for (int j = 0; j < 8; ++j) zp[j] = zacc[j];
    }

    // store acc: row m(d) = 16w + quad*4 + r, col e = j*16 + lrow
    float* mp = Mpart + ((size_t)split * 64 + g) * 4096;
#pragma unroll
    for (int j = 0; j < 4; ++j)
#pragma unroll
        for (int r = 0; r < 4; ++r)
            mp[(w * 16 + quad * 4 + r) * 64 + j * 16 + lrow] = acc[j][r];
}

// ---------- reduce partials + normalize: ctx2[g][d][e] = s * sum M / sum Z ----------
__global__ __launch_bounds__(256) void ctx_norm(const float* __restrict__ Mpart,
                                                const float* __restrict__ Zpart,
                                                float* __restrict__ ctx2) {
    const int g = blockIdx.x, t = threadIdx.x;
    __shared__ float rz[64];
    if (t < 64) {
        float zsum = 0.f;
#pragma unroll
        for (int s = 0; s < 16; ++s) zsum += Zpart[((size_t)s * 64 + g) * 64 + t];
        rz[t] = SCALE_S / zsum;
    }
    __syncthreads();
    for (int idx = t; idx < 4096; idx += 256) {
        float m = 0.f;
#pragma unroll
        for (int s = 0; s < 16; ++s) m += Mpart[((size_t)s * 64 + g) * 4096 + idx];
        ctx2[(size_t)g * 4096 + idx] = m * rz[idx >> 6];
    }
}

// ---------- W'T_b[j][h*64+d] = sum_e WoT[j][h*64+e] * ctx2[b,h][d][e] ----------
__global__ __launch_bounds__(256) void woprime(const float* __restrict__ ctx2,
                                               const u16* __restrict__ WoT,
                                               u16* __restrict__ WopT) {
    __shared__ float ctxT[64 * 65];          // [e][d], padded
    __shared__ __align__(16) u16 wo[64 * 64];
    const int t = threadIdx.x;
    const int jt = blockIdx.x, h = blockIdx.y, b = blockIdx.z;
    const int g = b * 16 + h;
    for (int idx = t; idx < 4096; idx += 256) {
        const int d = idx >> 6, e = idx & 63;
        ctxT[e * 65 + d] = ctx2[(size_t)g * 4096 + idx];
    }
    const int j0 = jt * 64;
#pragma unroll
    for (int c = 0; c < 2; ++c) {
        const int ii = c * 256 + t;
        const int j = ii >> 3, c8 = ii & 7;
        *(us8*)&wo[j * 64 + c8 * 8] = *(const us8*)&WoT[(size_t)(j0 + j) * 1024 + h * 64 + c8 * 8];
    }
    __syncthreads();
    const int d = t & 63, w = t >> 6;
    float accj[16] = {};
    for (int eb = 0; eb < 8; ++eb) {
        float c8[8];
#pragma unroll
        for (int e = 0; e < 8; ++e) c8[e] = ctxT[(eb * 8 + e) * 65 + d];
#pragma unroll
        for (int jj = 0; jj < 16; ++jj) {
            us8 w8 = *(const us8*)&wo[(jj * 4 + w) * 64 + eb * 8];   // wave-uniform broadcast
#pragma unroll
            for (int e = 0; e < 8; ++e)
                accj[jj] += bf2f((u16)w8[e]) * c8[e];
        }
    }
#pragma unroll
    for (int jj = 0; jj < 16; ++jj)
        WopT[(size_t)b * 1048576 + (size_t)(j0 + jj * 4 + w) * 1024 + h * 64 + d] = f2bf(accj[jj]);
}

// ---------- launch ----------
extern "C" void kernel_launch(void* const* d_in, const int* in_sizes, int n_in,
                              void* d_out, int out_size, void* d_ws, size_t ws_size,
                              hipStream_t stream)
{
    const float* x  = (const float*)d_in[0];
    const float* Wq = (const float*)d_in[1];
    const float* bq = (const float*)d_in[2];
    // d_in[3]=Wk, d_in[4]=bk : dead code in the reference, skipped
    const float* Wv = (const float*)d_in[5];
    const float* bv = (const float*)d_in[6];
    const float* Wo = (const float*)d_in[7];
    const float* bo = (const float*)d_in[8];
    float* out = (float*)d_out;

    char* ws = (char*)d_ws;
    size_t o = 0;
    auto alloc = [&](size_t bytes) { char* p = ws + o; o = (o + bytes + 255) & ~(size_t)255; return p; };
    u16*   x_bf  = (u16*)  alloc(16384ull * 1024 * 2);   // 32 MB (dead after GEMM1 -> reused as Mpart)
    u16*   WqvT  = (u16*)  alloc(2048ull * 1024 * 2);    //  4 MB
    u16*   WoT   = (u16*)  alloc(1024ull * 1024 * 2);    //  2 MB
    float* bqv   = (float*)alloc(2048ull * 4);
    u16*   qs    = (u16*)  alloc(16384ull * 1024 * 2);   // 32 MB
    u16*   vbuf  = (u16*)  alloc(16384ull * 1024 * 2);   // 32 MB
    float* Zpart = (float*)alloc(16ull * 64 * 64 * 4);
    float* ctx2  = (float*)alloc(64ull * 4096 * 4);      //  1 MB
    u16*   WopT  = (u16*)  alloc(4ull * 1024 * 1024 * 2);//  8 MB
    float* Mpart = (float*)x_bf;                         // 16 MB alias (x_bf dead by then)
    (void)ws_size; (void)in_sizes; (void)n_in; (void)out_size;

    convert_f32_bf16<<<8192, 256, 0, stream>>>(x, x_bf);
    transpose_convert3<<<dim3(32, 32, 3), dim3(32, 8), 0, stream>>>(Wq, Wv, Wo, WqvT, WoT);
    concat_bias<<<8, 256, 0, stream>>>(bq, bv, bqv);

    // QV projection + fused first softmax epilogue (256x256 8-phase)
    gemm_qv<<<dim3(64, 8), 512, 0, stream>>>(x_bf, WqvT, bqv, qs, vbuf);
    // second softmax (over seq) folded into MFMA-based weighted-sum partials
    ctx_mfma<<<dim3(64, 16), 256, 0, stream>>>(qs, vbuf, Mpart, Zpart);
    ctx_norm<<<64, 256, 0, stream>>>(Mpart, Zpart, ctx2);
    // W'_b = blockdiag(ctx2_b) @ Wo
    woprime<<<dim3(16, 16, 4), 256, 0, stream>>>(ctx2, WoT, WopT);
    // out = qs @ W'_b + bo (256x256 8-phase)
    gemm_out<<<dim3(16, 4, 4), 512, 0, stream>>>(qs, WopT, bo, out);
}

// Round 2
// 321.301 us; speedup vs baseline: 1.0031x; 1.0031x over previous
//
#include <hip/hip_runtime.h>

typedef unsigned short u16;
typedef __attribute__((ext_vector_type(8))) short short8;   // 8 bf16 (4 VGPRs) - MFMA A/B frag
typedef __attribute__((ext_vector_type(4))) float f4;       // MFMA C/D frag
typedef __attribute__((ext_vector_type(8))) unsigned short us8;

// ---------- helpers ----------
__device__ __forceinline__ u16 f2bf(float f) {              // RNE fp32 -> bf16
    unsigned u = __float_as_uint(f);
    u += 0x7FFFu + ((u >> 16) & 1u);
    return (u16)(u >> 16);
}
__device__ __forceinline__ float bf2f(u16 h) {
    return __uint_as_float(((unsigned)h) << 16);
}

#define GLD16(gp, lp) __builtin_amdgcn_global_load_lds( \
    (const __attribute__((address_space(1))) void*)(gp), \
    (__attribute__((address_space(3))) void*)(lp), 16, 0, 0)

// s = (d_head^0.5)^(-0.25) = 8^(-0.25)
#define SCALE_S 0.594603557501360533f

// ---------- fp32 -> bf16 (8 elems/thread) ----------
__global__ __launch_bounds__(256) void convert_f32_bf16(const float* __restrict__ in,
                                                        u16* __restrict__ out) {
    const size_t i = (size_t)blockIdx.x * 256 + threadIdx.x;
    const float4* p = (const float4*)in + i * 2;
    float4 a = p[0], b = p[1];
    us8 r;
    r[0] = f2bf(a.x); r[1] = f2bf(a.y); r[2] = f2bf(a.z); r[3] = f2bf(a.w);
    r[4] = f2bf(b.x); r[5] = f2bf(b.y); r[6] = f2bf(b.z); r[7] = f2bf(b.w);
    *(us8*)(out + i * 8) = r;
}

// ---------- transpose + convert x3: out[n][k] = bf16(W[k][n]), 1024x1024 ----------
__global__ __launch_bounds__(256) void transpose_convert3(
    const float* __restrict__ Wq, const float* __restrict__ Wv, const float* __restrict__ Wo,
    u16* __restrict__ WqvT, u16* __restrict__ WoT) {
    const float* W; u16* out;
    if (blockIdx.z == 0)      { W = Wq; out = WqvT; }
    else if (blockIdx.z == 1) { W = Wv; out = WqvT + 1024 * 1024; }
    else                      { W = Wo; out = WoT; }
    __shared__ float tile[32][33];
    const int tx = threadIdx.x, ty = threadIdx.y;   // 32 x 8
    const int x = blockIdx.x * 32 + tx;
#pragma unroll
    for (int i = 0; i < 4; ++i) {
        const int y = blockIdx.y * 32 + ty + i * 8;
        tile[ty + i * 8][tx] = W[(size_t)y * 1024 + x];
    }
    __syncthreads();
#pragma unroll
    for (int i = 0; i < 4; ++i) {
        const int yo = blockIdx.x * 32 + ty + i * 8;  // out row (= W col)
        const int xo = blockIdx.y * 32 + tx;          // out col (= W row)
        out[(size_t)yo * 1024 + xo] = f2bf(tile[tx][ty + i * 8]);
    }
}

__global__ void concat_bias(const float* __restrict__ bq, const float* __restrict__ bv,
                            float* __restrict__ bqv) {
    const int i = blockIdx.x * 256 + threadIdx.x;   // 0..2047
    bqv[i] = (i < 1024) ? bq[i] : bv[i - 1024];
}

// ============================================================================
// 256x256 8-phase GEMM core (T2 swizzle + T3/T4 counted-vmcnt + T5 setprio).
// 512 threads = 8 waves (2M x 4N), per-wave out 128x64, BK=64, LDS 128 KiB.
// MFMA operands SWAPPED (mfma(b, a, acc)) so each lane's 4 acc regs are 4
// CONSECUTIVE output columns (row = lrow) -> coalesced uint2/float4 stores.
// Ledger (per-wave GLD16 counts, 2 per half-tile):
//   prologue: stage B(k0),A(k0),B(k1) [12 loads]; vmcnt(4) -> k0 fully landed.
//   kt body:  p0 stages A0(kt+1), p1 A1(kt+1), p2 B0(kt+2), p3 B1(kt+2);
//             single vmcnt(4) before p3's end barrier -> A(kt+1)+B(kt+1) landed,
//             only B(kt+2) (4 loads) in flight. Never 0 in the loop.
//   B-frags ds_read once per K-tile at p0 and held in regs -> B slots free from p1.
//   A rows [32p,32p+32) read at phase p -> A(kt) slots never overwritten during kt.
// Last 2 K-tiles peeled after a single vmcnt(0) drain.
// ============================================================================
#define BAR8() do { asm volatile("" ::: "memory"); __builtin_amdgcn_s_barrier(); \
                    asm volatile("" ::: "memory"); } while (0)
#define WAITV(n) asm volatile("s_waitcnt vmcnt(" #n ")" ::: "memory")

// src already includes (row0)*1024 + swizzled col; half advances 128 rows, round +64 rows
#define STG(dst, src, dbuf, half, kt) do { \
    const u16* s_ = (src) + (size_t)(half) * 128 * 1024 + (size_t)(kt) * 64; \
    u16* d_ = &dst[dbuf][half][ldst]; \
    GLD16(s_, d_); \
    GLD16(s_ + (size_t)64 * 1024, d_ + 64 * 64); \
} while (0)

#define LOADB() do { \
    _Pragma("unroll") for (int j_ = 0; j_ < 4; ++j_) \
    _Pragma("unroll") for (int kk_ = 0; kk_ < 2; ++kk_) \
        bf[j_][kk_] = *(const short8*)&Bb[(brow + j_ * 16 + lrow) * 64 + (kg0 ^ (kk_ << 5))]; \
} while (0)

#define PHASE(p, STAGE_STMT, TAIL_WAIT) do { \
    short8 af[2][2]; \
    _Pragma("unroll") for (int i2_ = 0; i2_ < 2; ++i2_) \
    _Pragma("unroll") for (int kk_ = 0; kk_ < 2; ++kk_) \
        af[i2_][kk_] = *(const short8*)&Ab[(((p) * 2 + i2_) * 16 + lrow) * 64 + (kg0 ^ (kk_ << 5))]; \
    STAGE_STMT; \
    BAR8(); \
    __builtin_amdgcn_s_setprio(1); \
    _Pragma("unroll") for (int kk_ = 0; kk_ < 2; ++kk_) \
    _Pragma("unroll") for (int i2_ = 0; i2_ < 2; ++i2_) \
    _Pragma("unroll") for (int j_ = 0; j_ < 4; ++j_) \
        acc[(p) * 2 + i2_][j_] = __builtin_amdgcn_mfma_f32_16x16x32_bf16( \
            bf[j_][kk_], af[i2_][kk_], acc[(p) * 2 + i2_][j_], 0, 0, 0); \
    __builtin_amdgcn_s_setprio(0); \
    TAIL_WAIT; \
    BAR8(); \
} while (0)

// ---------- GEMM1: [x] @ [WqT;WvT]^T + bias, fused first-softmax epilogue ----------
__global__ __launch_bounds__(512, 2) void gemm_qv(
    const u16* __restrict__ A, const u16* __restrict__ BT,
    const float* __restrict__ bias,
    u16* __restrict__ qsOut, u16* __restrict__ vOut)
{
    __shared__ u16 As[2][2][128 * 64];
    __shared__ u16 Bs[2][2][128 * 64];
    const int t = threadIdx.x;
    const int l = t & 63, w = t >> 6;
    const int quad = l >> 4, lrow = l & 15;
    const int wrow = w >> 2, wcol = w & 3;
    const int bhalf = wcol >> 1, brow = (wcol & 1) * 64;

    int bx, by;
    {
        const int id = blockIdx.x + (int)gridDim.x * blockIdx.y;
        const int xcd = id & 7, j = id >> 3;
        const int xs = (int)gridDim.x >> 3;
        bx = xcd * xs + (j % xs);
        by = j / xs;
    }
    const int m0 = bx * 256, n0 = by * 256;

    const int lr0 = t >> 3;                      // row within half (0..63)
    const int cg = ((t & 7) ^ (lr0 & 7)) * 8;    // swizzled k-granule
    const int ldst = lr0 * 64 + (t & 7) * 8;     // LDS dst = uniform + lane*16B
    const u16* aS = A  + (size_t)(m0 + lr0) * 1024 + cg;
    const u16* bS = BT + (size_t)(n0 + lr0) * 1024 + cg;

    const int kg0 = (quad ^ (lrow & 7)) << 3;
    f4 acc[8][4] = {};

    // prologue: k0 full + B(k1)
    STG(Bs, bS, 0, 0, 0); STG(Bs, bS, 0, 1, 0);
    STG(As, aS, 0, 0, 0); STG(As, aS, 0, 1, 0);
    STG(Bs, bS, 1, 0, 1); STG(Bs, bS, 1, 1, 1);
    WAITV(4);
    BAR8();

    for (int kt = 0; kt < 14; ++kt) {
        const int d = kt & 1;
        const u16* Ab = As[d][wrow];
        const u16* Bb = Bs[d][bhalf];
        short8 bf[4][2];
        LOADB();
        PHASE(0, STG(As, aS, d ^ 1, 0, kt + 1), (void)0);
        PHASE(1, STG(As, aS, d ^ 1, 1, kt + 1), (void)0);
        PHASE(2, STG(Bs, bS, d, 0, kt + 2), (void)0);
        PHASE(3, STG(Bs, bS, d, 1, kt + 2), WAITV(4));
    }
    // peel kt=14,15: only A(15) remains unstaged
    STG(As, aS, 1, 0, 15); STG(As, aS, 1, 1, 15);
    WAITV(0);
    BAR8();
#pragma unroll
    for (int kt = 14; kt < 16; ++kt) {
        const int d = kt & 1;
        const u16* Ab = As[d][wrow];
        const u16* Bb = Bs[d][bhalf];
        short8 bf[4][2];
        LOADB();
#pragma unroll
        for (int p = 0; p < 4; ++p) {
            short8 af[2][2];
#pragma unroll
            for (int i2 = 0; i2 < 2; ++i2)
#pragma unroll
                for (int kk = 0; kk < 2; ++kk)
                    af[i2][kk] = *(const short8*)&Ab[((p * 2 + i2) * 16 + lrow) * 64 + (kg0 ^ (kk << 5))];
#pragma unroll
            for (int kk = 0; kk < 2; ++kk)
#pragma unroll
                for (int i2 = 0; i2 < 2; ++i2)
#pragma unroll
                    for (int j = 0; j < 4; ++j)
                        acc[p * 2 + i2][j] = __builtin_amdgcn_mfma_f32_16x16x32_bf16(
                            bf[j][kk], af[i2][kk], acc[p * 2 + i2][j], 0, 0, 0);
        }
    }

    // epilogue (swapped layout): row m = ... + lrow; lane's acc[i][j][r] = col
    // n0 + wcol*64 + j*16 + quad*4 + r. Head = wave's 64-col span.
    const int colh = n0 + wcol * 64;
    const bool isQ = n0 < 1024;                 // block-uniform (256-wide tiles)
    float4 bs4[4];
#pragma unroll
    for (int j = 0; j < 4; ++j)
        bs4[j] = *(const float4*)&bias[colh + j * 16 + quad * 4];

#pragma unroll
    for (int i = 0; i < 8; ++i) {
        const int m = m0 + wrow * 128 + i * 16 + lrow;
        float v[4][4];
#pragma unroll
        for (int j = 0; j < 4; ++j) {
            v[j][0] = acc[i][j][0] + bs4[j].x;
            v[j][1] = acc[i][j][1] + bs4[j].y;
            v[j][2] = acc[i][j][2] + bs4[j].z;
            v[j][3] = acc[i][j][3] + bs4[j].w;
        }
        if (isQ) {
            float mx = v[0][0];
#pragma unroll
            for (int j = 0; j < 4; ++j)
#pragma unroll
                for (int r = 0; r < 4; ++r) mx = fmaxf(mx, v[j][r]);
            mx = fmaxf(mx, __shfl_xor(mx, 16));
            mx = fmaxf(mx, __shfl_xor(mx, 32));
            float sm = 0.f;
#pragma unroll
            for (int j = 0; j < 4; ++j)
#pragma unroll
                for (int r = 0; r < 4; ++r) { v[j][r] = __expf(v[j][r] - mx); sm += v[j][r]; }
            sm += __shfl_xor(sm, 16);
            sm += __shfl_xor(sm, 32);
            const float inv = SCALE_S / sm;
            u16* qp = qsOut + (size_t)m * 1024 + colh + quad * 4;
#pragma unroll
            for (int j = 0; j < 4; ++j) {
                uint2 pk;
                pk.x = (unsigned)f2bf(v[j][0] * inv) | ((unsigned)f2bf(v[j][1] * inv) << 16);
                pk.y = (unsigned)f2bf(v[j][2] * inv) | ((unsigned)f2bf(v[j][3] * inv) << 16);
                *(uint2*)(qp + j * 16) = pk;
            }
        } else {
            u16* vp = vOut + (size_t)m * 1024 + (colh - 1024) + quad * 4;
#pragma unroll
            for (int j = 0; j < 4; ++j) {
                uint2 pk;
                pk.x = (unsigned)f2bf(v[j][0]) | ((unsigned)f2bf(v[j][1]) << 16);
                pk.y = (unsigned)f2bf(v[j][2]) | ((unsigned)f2bf(v[j][3]) << 16);
                *(uint2*)(vp + j * 16) = pk;
            }
        }
    }
}

// ---------- GEMM3: out[z] = qs[z] @ WopT[z]^T + bo (fp32 store) ----------
__global__ __launch_bounds__(512, 2) void gemm_out(
    const u16* __restrict__ A, const u16* __restrict__ BT,
    const float* __restrict__ bias, float* __restrict__ C)
{
    __shared__ u16 As[2][2][128 * 64];
    __shared__ u16 Bs[2][2][128 * 64];
    const int t = threadIdx.x;
    const int l = t & 63, w = t >> 6;
    const int quad = l >> 4, lrow = l & 15;
    const int wrow = w >> 2, wcol = w & 3;
    const int bhalf = wcol >> 1, brow = (wcol & 1) * 64;
    const int z = blockIdx.z;
    A  += (size_t)z * (4096 * 1024);
    BT += (size_t)z * (1024 * 1024);
    C  += (size_t)z * (4096 * 1024);

    int bx, by;
    {
        const int id = blockIdx.x + (int)gridDim.x * blockIdx.y;
        const int xcd = id & 7, j = id >> 3;
        const int xs = (int)gridDim.x >> 3;    // 2
        bx = xcd * xs + (j % xs);
        by = j / xs;
    }
    const int m0 = bx * 256, n0 = by * 256;

    const int lr0 = t >> 3;
    const int cg = ((t & 7) ^ (lr0 & 7)) * 8;
    const int ldst = lr0 * 64 + (t & 7) * 8;
    const u16* aS = A  + (size_t)(m0 + lr0) * 1024 + cg;
    const u16* bS = BT + (size_t)(n0 + lr0) * 1024 + cg;

    const int kg0 = (quad ^ (lrow & 7)) << 3;
    f4 acc[8][4] = {};

    STG(Bs, bS, 0, 0, 0); STG(Bs, bS, 0, 1, 0);
    STG(As, aS, 0, 0, 0); STG(As, aS, 0, 1, 0);
    STG(Bs, bS, 1, 0, 1); STG(Bs, bS, 1, 1, 1);
    WAITV(4);
    BAR8();

    for (int kt = 0; kt < 14; ++kt) {
        const int d = kt & 1;
        const u16* Ab = As[d][wrow];
        const u16* Bb = Bs[d][bhalf];
        short8 bf[4][2];
        LOADB();
        PHASE(0, STG(As, aS, d ^ 1, 0, kt + 1), (void)0);
        PHASE(1, STG(As, aS, d ^ 1, 1, kt + 1), (void)0);
        PHASE(2, STG(Bs, bS, d, 0, kt + 2), (void)0);
        PHASE(3, STG(Bs, bS, d, 1, kt + 2), WAITV(4));
    }
    STG(As, aS, 1, 0, 15); STG(As, aS, 1, 1, 15);
    WAITV(0);
    BAR8();
#pragma unroll
    for (int kt = 14; kt < 16; ++kt) {
        const int d = kt & 1;
        const u16* Ab = As[d][wrow];
        const u16* Bb = Bs[d][bhalf];
        short8 bf[4][2];
        LOADB();
#pragma unroll
        for (int p = 0; p < 4; ++p) {
            short8 af[2][2];
#pragma unroll
            for (int i2 = 0; i2 < 2; ++i2)
#pragma unroll
                for (int kk = 0; kk < 2; ++kk)
                    af[i2][kk] = *(const short8*)&Ab[((p * 2 + i2) * 16 + lrow) * 64 + (kg0 ^ (kk << 5))];
#pragma unroll
            for (int kk = 0; kk < 2; ++kk)
#pragma unroll
                for (int i2 = 0; i2 < 2; ++i2)
#pragma unroll
                    for (int j = 0; j < 4; ++j)
                        acc[p * 2 + i2][j] = __builtin_amdgcn_mfma_f32_16x16x32_bf16(
                            bf[j][kk], af[i2][kk], acc[p * 2 + i2][j], 0, 0, 0);
        }
    }

    // epilogue (swapped layout): float4 coalesced stores
    const int colh = n0 + wcol * 64;
    float4 bs4[4];
#pragma unroll
    for (int j = 0; j < 4; ++j)
        bs4[j] = *(const float4*)&bias[colh + j * 16 + quad * 4];
#pragma unroll
    for (int i = 0; i < 8; ++i) {
        const int m = m0 + wrow * 128 + i * 16 + lrow;
        float* cp = C + (size_t)m * 1024 + colh + quad * 4;
#pragma unroll
        for (int j = 0; j < 4; ++j) {
            float4 o;
            o.x = acc[i][j][0] + bs4[j].x;
            o.y = acc[i][j][1] + bs4[j].y;
            o.z = acc[i][j][2] + bs4[j].z;
            o.w = acc[i][j][3] + bs4[j].w;
            *(float4*)(cp + j * 16) = o;
        }
    }
}

// ---------- ctx partials via MFMA: Mpart[split][g][d][e] = sum_n exp(qs[n,d]) * v[n,e] ----
__global__ __launch_bounds__(256) void ctx_mfma(
    const u16* __restrict__ qs, const u16* __restrict__ vb,
    float* __restrict__ Mpart, float* __restrict__ Zpart)
{
    __shared__ __align__(16) u16 Et[2][64 * 64];
    __shared__ __align__(16) u16 Vt[2][64 * 64];
    const int t = threadIdx.x;
    const int w = t >> 6, l = t & 63;
    const int quad = l >> 4, lrow = l & 15;
    const int g = blockIdx.x;          // b = g>>4, h = g&15
    const int split = blockIdx.y;      // 0..15
    const int b = g >> 4, h = g & 15;

    const int n0 = (l & 31) * 2;       // rows n0, n0+1 within slab
    const int d0 = w * 16 + (l >> 5) * 8;
    const u16* qp = qs + ((size_t)b * 4096 + (size_t)split * 256 + n0) * 1024 + h * 64 + d0;
    const u16* vp = vb + ((size_t)b * 4096 + (size_t)split * 256 + n0) * 1024 + h * 64 + d0;

    f4 acc[4] = {};
    float zacc[8] = {};

    us8 q8a = *(const us8*)qp;
    us8 q8b = *(const us8*)(qp + 1024);
    us8 v8a = *(const us8*)vp;
    us8 v8b = *(const us8*)(vp + 1024);

    for (int slab = 0; slab < 4; ++slab) {
        unsigned epk[8], vpk[8];
#pragma unroll
        for (int j = 0; j < 8; ++j) {
            float ea = __expf(bf2f((u16)q8a[j]));
            float eb = __expf(bf2f((u16)q8b[j]));
            zacc[j] += ea + eb;
            epk[j] = (unsigned)f2bf(ea) | ((unsigned)f2bf(eb) << 16);
            vpk[j] = (unsigned)(u16)v8a[j] | ((unsigned)(u16)v8b[j] << 16);
        }
        if (slab < 3) {                // prefetch next slab (overlaps sync+MFMA below)
            qp += 64 * 1024; vp += 64 * 1024;
            q8a = *(const us8*)qp;  q8b = *(const us8*)(qp + 1024);
            v8a = *(const us8*)vp;  v8b = *(const us8*)(vp + 1024);
        }
        u16* et = Et[slab & 1];
        u16* vt = Vt[slab & 1];
#pragma unroll
        for (int j = 0; j < 8; ++j) {
            const int d = d0 + j;
            const int off = d * 64 + (((n0 >> 3) ^ (d & 7)) << 3) + (n0 & 7);
            *(unsigned*)&et[off] = epk[j];
            *(unsigned*)&vt[off] = vpk[j];
        }
        __syncthreads();
#pragma unroll
        for (int kk = 0; kk < 2; ++kk) {
            const int blk = ((kk * 4 + quad) ^ (lrow & 7)) << 3;
            short8 a = *(const short8*)&et[(w * 16 + lrow) * 64 + blk];
#pragma unroll
            for (int j = 0; j < 4; ++j) {
                short8 bfr = *(const short8*)&vt[(j * 16 + lrow) * 64 + blk];
                acc[j] = __builtin_amdgcn_mfma_f32_16x16x32_bf16(bfr, a, acc[j], 0, 0, 0);
            }
        }
    }

    // Z: butterfly within each 32-lane half (all lanes of a half share d0-range)
#pragma unroll
    for (int j = 0; j < 8; ++j) {
        zacc[j] += __shfl_xor(zacc[j], 1);
        zacc[j] += __shfl_xor(zacc[j], 2);
        zacc[j] += __shfl_xor(zacc[j], 4);
        zacc[j] += __shfl_xor(zacc[j], 8);
        zacc[j] += __shfl_xor(zacc[j], 16);
    }
    if ((l & 31) == 0) {
        float* zp = Zpart + ((size_t)split * 64 + g) * 64 + d0;
#pragma unroll
        for (int j = 0; j < 8; ++j) zp[j] = zacc[j];
    }

    // store acc (swapped layout): d = w*16 + lrow, e = j*16 + quad*4 + r -> float4
    float* mp = Mpart + ((size_t)split * 64 + g) * 4096;
#pragma unroll
    for (int j = 0; j < 4; ++j) {
        float4 o;
        o.x = acc[j][0]; o.y = acc[j][1]; o.z = acc[j][2]; o.w = acc[j][3];
        *(float4*)&mp[(w * 16 + lrow) * 64 + j * 16 + quad * 4] = o;
    }
}

// ---------- reduce partials + normalize: ctx2[g][d][e] = s * sum M / sum Z ----------
__global__ __launch_bounds__(256) void ctx_norm(const float* __restrict__ Mpart,
                                                const float* __restrict__ Zpart,
                                                float* __restrict__ ctx2) {
    const int g = blockIdx.x, t = threadIdx.x;
    __shared__ float rz[64];
    if (t < 64) {
        float zsum = 0.f;
#pragma unroll
        for (int s = 0; s < 16; ++s) zsum += Zpart[((size_t)s * 64 + g) * 64 + t];
        rz[t] = SCALE_S / zsum;
    }
    __syncthreads();
    for (int idx = t; idx < 4096; idx += 256) {
        float m = 0.f;
#pragma unroll
        for (int s = 0; s < 16; ++s) m += Mpart[((size_t)s * 64 + g) * 4096 + idx];
        ctx2[(size_t)g * 4096 + idx] = m * rz[idx >> 6];
    }
}

// ---------- W'T_b[j][h*64+d] = sum_e WoT[j][h*64+e] * ctx2[b,h][d][e] ----------
__global__ __launch_bounds__(256) void woprime(const float* __restrict__ ctx2,
                                               const u16* __restrict__ WoT,
                                               u16* __restrict__ WopT) {
    __shared__ float ctxT[64 * 65];          // [e][d], padded
    __shared__ __align__(16) u16 wo[64 * 64];
    const int t = threadIdx.x;
    const int jt = blockIdx.x, h = blockIdx.y, b = blockIdx.z;
    const int g = b * 16 + h;
    for (int idx = t; idx < 4096; idx += 256) {
        const int d = idx >> 6, e = idx & 63;
        ctxT[e * 65 + d] = ctx2[(size_t)g * 4096 + idx];
    }
    const int j0 = jt * 64;
#pragma unroll
    for (int c = 0; c < 2; ++c) {
        const int ii = c * 256 + t;
        const int j = ii >> 3, c8 = ii & 7;
        *(us8*)&wo[j * 64 + c8 * 8] = *(const us8*)&WoT[(size_t)(j0 + j) * 1024 + h * 64 + c8 * 8];
    }
    __syncthreads();
    const int d = t & 63, w = t >> 6;
    float accj[16] = {};
    for (int eb = 0; eb < 8; ++eb) {
        float c8[8];
#pragma unroll
        for (int e = 0; e < 8; ++e) c8[e] = ctxT[(eb * 8 + e) * 65 + d];
#pragma unroll
        for (int jj = 0; jj < 16; ++jj) {
            us8 w8 = *(const us8*)&wo[(jj * 4 + w) * 64 + eb * 8];   // wave-uniform broadcast
#pragma unroll
            for (int e = 0; e < 8; ++e)
                accj[jj] += bf2f((u16)w8[e]) * c8[e];
        }
    }
#pragma unroll
    for (int jj = 0; jj < 16; ++jj)
        WopT[(size_t)b * 1048576 + (size_t)(j0 + jj * 4 + w) * 1024 + h * 64 + d] = f2bf(accj[jj]);
}

// ---------- launch ----------
extern "C" void kernel_launch(void* const* d_in, const int* in_sizes, int n_in,
                              void* d_out, int out_size, void* d_ws, size_t ws_size,
                              hipStream_t stream)
{
    const float* x  = (const float*)d_in[0];
    const float* Wq = (const float*)d_in[1];
    const float* bq = (const float*)d_in[2];
    // d_in[3]=Wk, d_in[4]=bk : dead code in the reference, skipped
    const float* Wv = (const float*)d_in[5];
    const float* bv = (const float*)d_in[6];
    const float* Wo = (const float*)d_in[7];
    const float* bo = (const float*)d_in[8];
    float* out = (float*)d_out;

    char* ws = (char*)d_ws;
    size_t o = 0;
    auto alloc = [&](size_t bytes) { char* p = ws + o; o = (o + bytes + 255) & ~(size_t)255; return p; };
    u16*   x_bf  = (u16*)  alloc(16384ull * 1024 * 2);   // 32 MB (dead after GEMM1 -> reused as Mpart)
    u16*   WqvT  = (u16*)  alloc(2048ull * 1024 * 2);    //  4 MB
    u16*   WoT   = (u16*)  alloc(1024ull * 1024 * 2);    //  2 MB
    float* bqv   = (float*)alloc(2048ull * 4);
    u16*   qs    = (u16*)  alloc(16384ull * 1024 * 2);   // 32 MB
    u16*   vbuf  = (u16*)  alloc(16384ull * 1024 * 2);   // 32 MB
    float* Zpart = (float*)alloc(16ull * 64 * 64 * 4);
    float* ctx2  = (float*)alloc(64ull * 4096 * 4);      //  1 MB
    u16*   WopT  = (u16*)  alloc(4ull * 1024 * 1024 * 2);//  8 MB
    float* Mpart = (float*)x_bf;                         // 16 MB alias (x_bf dead by then)
    (void)ws_size; (void)in_sizes; (void)n_in; (void)out_size;

    convert_f32_bf16<<<8192, 256, 0, stream>>>(x, x_bf);
    transpose_convert3<<<dim3(32, 32, 3), dim3(32, 8), 0, stream>>>(Wq, Wv, Wo, WqvT, WoT);
    concat_bias<<<8, 256, 0, stream>>>(bq, bv, bqv);

    // QV projection + fused first softmax epilogue (256x256 8-phase)
    gemm_qv<<<dim3(64, 8), 512, 0, stream>>>(x_bf, WqvT, bqv, qs, vbuf);
    // second softmax (over seq) folded into MFMA-based weighted-sum partials
    ctx_mfma<<<dim3(64, 16), 256, 0, stream>>>(qs, vbuf, Mpart, Zpart);
    ctx_norm<<<64, 256, 0, stream>>>(Mpart, Zpart, ctx2);
    // W'_b = blockdiag(ctx2_b) @ Wo
    woprime<<<dim3(16, 16, 4), 256, 0, stream>>>(ctx2, WoT, WopT);
    // out = qs @ W'_b + bo (256x256 8-phase)
    gemm_out<<<dim3(16, 4, 4), 512, 0, stream>>>(qs, WopT, bo, out);
}

// Round 3
// 303.282 us; speedup vs baseline: 1.0627x; 1.0594x over previous
//
#include <hip/hip_runtime.h>

typedef unsigned short u16;
typedef __attribute__((ext_vector_type(8))) short short8;   // 8 bf16 (4 VGPRs) - MFMA A/B frag
typedef __attribute__((ext_vector_type(4))) float f4;       // MFMA C/D frag
typedef __attribute__((ext_vector_type(8))) unsigned short us8;

// ---------- helpers ----------
__device__ __forceinline__ u16 f2bf(float f) {              // RNE fp32 -> bf16
    unsigned u = __float_as_uint(f);
    u += 0x7FFFu + ((u >> 16) & 1u);
    return (u16)(u >> 16);
}
__device__ __forceinline__ float bf2f(u16 h) {
    return __uint_as_float(((unsigned)h) << 16);
}

#define GLD16(gp, lp) __builtin_amdgcn_global_load_lds( \
    (const __attribute__((address_space(1))) void*)(gp), \
    (__attribute__((address_space(3))) void*)(lp), 16, 0, 0)

// s = (d_head^0.5)^(-0.25) = 8^(-0.25)
#define SCALE_S 0.594603557501360533f

// ---------- fp32 -> bf16 (8 elems/thread) ----------
__global__ __launch_bounds__(256) void convert_f32_bf16(const float* __restrict__ in,
                                                        u16* __restrict__ out) {
    const size_t i = (size_t)blockIdx.x * 256 + threadIdx.x;
    const float4* p = (const float4*)in + i * 2;
    float4 a = p[0], b = p[1];
    us8 r;
    r[0] = f2bf(a.x); r[1] = f2bf(a.y); r[2] = f2bf(a.z); r[3] = f2bf(a.w);
    r[4] = f2bf(b.x); r[5] = f2bf(b.y); r[6] = f2bf(b.z); r[7] = f2bf(b.w);
    *(us8*)(out + i * 8) = r;
}

// ---------- transpose + convert x3: out[n][k] = bf16(W[k][n]), 1024x1024 ----------
__global__ __launch_bounds__(256) void transpose_convert3(
    const float* __restrict__ Wq, const float* __restrict__ Wv, const float* __restrict__ Wo,
    u16* __restrict__ WqvT, u16* __restrict__ WoT) {
    const float* W; u16* out;
    if (blockIdx.z == 0)      { W = Wq; out = WqvT; }
    else if (blockIdx.z == 1) { W = Wv; out = WqvT + 1024 * 1024; }
    else                      { W = Wo; out = WoT; }
    __shared__ float tile[32][33];
    const int tx = threadIdx.x, ty = threadIdx.y;   // 32 x 8
    const int x = blockIdx.x * 32 + tx;
#pragma unroll
    for (int i = 0; i < 4; ++i) {
        const int y = blockIdx.y * 32 + ty + i * 8;
        tile[ty + i * 8][tx] = W[(size_t)y * 1024 + x];
    }
    __syncthreads();
#pragma unroll
    for (int i = 0; i < 4; ++i) {
        const int yo = blockIdx.x * 32 + ty + i * 8;  // out row (= W col)
        const int xo = blockIdx.y * 32 + tx;          // out col (= W row)
        out[(size_t)yo * 1024 + xo] = f2bf(tile[tx][ty + i * 8]);
    }
}

__global__ void concat_bias(const float* __restrict__ bq, const float* __restrict__ bv,
                            float* __restrict__ bqv) {
    const int i = blockIdx.x * 256 + threadIdx.x;   // 0..2047
    bqv[i] = (i < 1024) ? bq[i] : bv[i - 1024];
}

// ============================================================================
// 256x256 8-phase GEMM core. STATIC double-buffer split (As0/As1/Bs0/Bs1) so
// the compiler's LDS-DMA alias tracking can prove each phase's ds_reads don't
// touch in-flight global_load_lds writes -> no compiler-inserted vmcnt drains;
// the explicit counted vmcnt(4) is the only wait (T4).
// Ledger (per-wave, 2 GLD16 per half-tile):
//   prologue: B(0)->Bs0, A(0)->As0, B(1)->Bs1 [12 loads]; vmcnt(4): k0 landed.
//   even kt:  reads As0,Bs0; p0/p1 stage A(kt+1)->As1, p2/p3 B(kt+2)->Bs0;
//             vmcnt(4) at p3 -> A(kt+1)+B(kt+1) landed, B(kt+2) in flight.
//   odd kt:   reads As1,Bs1; p0/p1 stage A(kt+2)->As0, p2/p3 B(kt+3)->Bs1;
//             vmcnt(4) at p3 -> A(kt+2)+B(kt+2) landed, B(kt+3) in flight.
//   Entering any kt, all pending DMA writes target arrays NOT read this kt.
// Last 2 K-tiles peeled after a single vmcnt(0) drain.
// MFMA operands SWAPPED (mfma(b, a, acc)): lane's 4 acc regs = 4 consecutive
// output COLUMNS (row = lrow) -> coalesced uint2/float4 epilogue stores.
// ============================================================================
#define BAR8() do { asm volatile("" ::: "memory"); __builtin_amdgcn_s_barrier(); \
                    asm volatile("" ::: "memory"); } while (0)
#define WAITV(n) asm volatile("s_waitcnt vmcnt(" #n ")" ::: "memory")

// src already includes (row0)*1024 + swizzled col; half advances 128 rows, round +64 rows
#define STG2(arr, src, half, kt) do { \
    const u16* s_ = (src) + (size_t)(half) * 128 * 1024 + (size_t)(kt) * 64; \
    u16* d_ = &arr[half][ldst]; \
    GLD16(s_, d_); \
    GLD16(s_ + (size_t)64 * 1024, d_ + 64 * 64); \
} while (0)

#define LOADB() do { \
    _Pragma("unroll") for (int j_ = 0; j_ < 4; ++j_) \
    _Pragma("unroll") for (int kk_ = 0; kk_ < 2; ++kk_) \
        bf[j_][kk_] = *(const short8*)&Bb[(brow + j_ * 16 + lrow) * 64 + (kg0 ^ (kk_ << 5))]; \
} while (0)

#define PHASE(p, STAGE_STMT, TAIL_WAIT) do { \
    short8 af[2][2]; \
    _Pragma("unroll") for (int i2_ = 0; i2_ < 2; ++i2_) \
    _Pragma("unroll") for (int kk_ = 0; kk_ < 2; ++kk_) \
        af[i2_][kk_] = *(const short8*)&Ab[(((p) * 2 + i2_) * 16 + lrow) * 64 + (kg0 ^ (kk_ << 5))]; \
    STAGE_STMT; \
    BAR8(); \
    __builtin_amdgcn_s_setprio(1); \
    _Pragma("unroll") for (int kk_ = 0; kk_ < 2; ++kk_) \
    _Pragma("unroll") for (int i2_ = 0; i2_ < 2; ++i2_) \
    _Pragma("unroll") for (int j_ = 0; j_ < 4; ++j_) \
        acc[(p) * 2 + i2_][j_] = __builtin_amdgcn_mfma_f32_16x16x32_bf16( \
            bf[j_][kk_], af[i2_][kk_], acc[(p) * 2 + i2_][j_], 0, 0, 0); \
    __builtin_amdgcn_s_setprio(0); \
    TAIL_WAIT; \
    BAR8(); \
} while (0)

// peeled K-tile: no staging, no barriers (all data resident, no writes)
#define KTILE_NOSYNC(AsX, BsX) do { \
    const u16* Ab = AsX[wrow]; \
    const u16* Bb = BsX[bhalf]; \
    short8 bf[4][2]; \
    LOADB(); \
    _Pragma("unroll") for (int p_ = 0; p_ < 4; ++p_) { \
        short8 af[2][2]; \
        _Pragma("unroll") for (int i2_ = 0; i2_ < 2; ++i2_) \
        _Pragma("unroll") for (int kk_ = 0; kk_ < 2; ++kk_) \
            af[i2_][kk_] = *(const short8*)&Ab[((p_ * 2 + i2_) * 16 + lrow) * 64 + (kg0 ^ (kk_ << 5))]; \
        _Pragma("unroll") for (int kk_ = 0; kk_ < 2; ++kk_) \
        _Pragma("unroll") for (int i2_ = 0; i2_ < 2; ++i2_) \
        _Pragma("unroll") for (int j_ = 0; j_ < 4; ++j_) \
            acc[p_ * 2 + i2_][j_] = __builtin_amdgcn_mfma_f32_16x16x32_bf16( \
                bf[j_][kk_], af[i2_][kk_], acc[p_ * 2 + i2_][j_], 0, 0, 0); \
    } \
} while (0)

// ---------- GEMM1: [x] @ [WqT;WvT]^T + bias, fused first-softmax epilogue ----------
__global__ __launch_bounds__(512, 2) void gemm_qv(
    const u16* __restrict__ A, const u16* __restrict__ BT,
    const float* __restrict__ bias,
    u16* __restrict__ qsOut, u16* __restrict__ vOut)
{
    __shared__ u16 As0[2][128 * 64], As1[2][128 * 64];
    __shared__ u16 Bs0[2][128 * 64], Bs1[2][128 * 64];
    const int t = threadIdx.x;
    const int l = t & 63, w = t >> 6;
    const int quad = l >> 4, lrow = l & 15;
    const int wrow = w >> 2, wcol = w & 3;
    const int bhalf = wcol >> 1, brow = (wcol & 1) * 64;

    int bx, by;
    {
        const int id = blockIdx.x + (int)gridDim.x * blockIdx.y;
        const int xcd = id & 7, j = id >> 3;
        const int xs = (int)gridDim.x >> 3;
        bx = xcd * xs + (j % xs);
        by = j / xs;
    }
    const int m0 = bx * 256, n0 = by * 256;

    const int lr0 = t >> 3;                      // row within half (0..63)
    const int cg = ((t & 7) ^ (lr0 & 7)) * 8;    // swizzled k-granule
    const int ldst = lr0 * 64 + (t & 7) * 8;     // LDS dst = uniform + lane*16B
    const u16* aS = A  + (size_t)(m0 + lr0) * 1024 + cg;
    const u16* bS = BT + (size_t)(n0 + lr0) * 1024 + cg;

    const int kg0 = (quad ^ (lrow & 7)) << 3;
    f4 acc[8][4] = {};

    // prologue: k0 full + B(k1)
    STG2(Bs0, bS, 0, 0); STG2(Bs0, bS, 1, 0);
    STG2(As0, aS, 0, 0); STG2(As0, aS, 1, 0);
    STG2(Bs1, bS, 0, 1); STG2(Bs1, bS, 1, 1);
    WAITV(4);
    BAR8();

    for (int kt2 = 0; kt2 < 7; ++kt2) {
        const int kt = kt2 * 2;
        {   // even kt: read As0,Bs0; stage A(kt+1)->As1, B(kt+2)->Bs0
            const u16* Ab = As0[wrow];
            const u16* Bb = Bs0[bhalf];
            short8 bf[4][2];
            LOADB();
            PHASE(0, STG2(As1, aS, 0, kt + 1), (void)0);
            PHASE(1, STG2(As1, aS, 1, kt + 1), (void)0);
            PHASE(2, STG2(Bs0, bS, 0, kt + 2), (void)0);
            PHASE(3, STG2(Bs0, bS, 1, kt + 2), WAITV(4));
        }
        {   // odd kt+1: read As1,Bs1; stage A(kt+2)->As0, B(kt+3)->Bs1
            const u16* Ab = As1[wrow];
            const u16* Bb = Bs1[bhalf];
            short8 bf[4][2];
            LOADB();
            PHASE(0, STG2(As0, aS, 0, kt + 2), (void)0);
            PHASE(1, STG2(As0, aS, 1, kt + 2), (void)0);
            PHASE(2, STG2(Bs1, bS, 0, kt + 3), (void)0);
            PHASE(3, STG2(Bs1, bS, 1, kt + 3), WAITV(4));
        }
    }
    // kt=0..13 done. In LDS: A(14)->As0, B(14)->Bs0, B(15)->Bs1. Stage A(15):
    STG2(As1, aS, 0, 15); STG2(As1, aS, 1, 15);
    WAITV(0);
    BAR8();
    KTILE_NOSYNC(As0, Bs0);   // kt=14
    KTILE_NOSYNC(As1, Bs1);   // kt=15

    // epilogue (swapped layout): row m = ... + lrow; lane's acc[i][j][r] = col
    // n0 + wcol*64 + j*16 + quad*4 + r. Head = wave's 64-col span.
    const int colh = n0 + wcol * 64;
    const bool isQ = n0 < 1024;                 // block-uniform (256-wide tiles)
    float4 bs4[4];
#pragma unroll
    for (int j = 0; j < 4; ++j)
        bs4[j] = *(const float4*)&bias[colh + j * 16 + quad * 4];

#pragma unroll
    for (int i = 0; i < 8; ++i) {
        const int m = m0 + wrow * 128 + i * 16 + lrow;
        float v[4][4];
#pragma unroll
        for (int j = 0; j < 4; ++j) {
            v[j][0] = acc[i][j][0] + bs4[j].x;
            v[j][1] = acc[i][j][1] + bs4[j].y;
            v[j][2] = acc[i][j][2] + bs4[j].z;
            v[j][3] = acc[i][j][3] + bs4[j].w;
        }
        if (isQ) {
            float mx = v[0][0];
#pragma unroll
            for (int j = 0; j < 4; ++j)
#pragma unroll
                for (int r = 0; r < 4; ++r) mx = fmaxf(mx, v[j][r]);
            mx = fmaxf(mx, __shfl_xor(mx, 16));
            mx = fmaxf(mx, __shfl_xor(mx, 32));
            float sm = 0.f;
#pragma unroll
            for (int j = 0; j < 4; ++j)
#pragma unroll
                for (int r = 0; r < 4; ++r) { v[j][r] = __expf(v[j][r] - mx); sm += v[j][r]; }
            sm += __shfl_xor(sm, 16);
            sm += __shfl_xor(sm, 32);
            const float inv = SCALE_S / sm;
            u16* qp = qsOut + (size_t)m * 1024 + colh + quad * 4;
#pragma unroll
            for (int j = 0; j < 4; ++j) {
                uint2 pk;
                pk.x = (unsigned)f2bf(v[j][0] * inv) | ((unsigned)f2bf(v[j][1] * inv) << 16);
                pk.y = (unsigned)f2bf(v[j][2] * inv) | ((unsigned)f2bf(v[j][3] * inv) << 16);
                *(uint2*)(qp + j * 16) = pk;
            }
        } else {
            u16* vp = vOut + (size_t)m * 1024 + (colh - 1024) + quad * 4;
#pragma unroll
            for (int j = 0; j < 4; ++j) {
                uint2 pk;
                pk.x = (unsigned)f2bf(v[j][0]) | ((unsigned)f2bf(v[j][1]) << 16);
                pk.y = (unsigned)f2bf(v[j][2]) | ((unsigned)f2bf(v[j][3]) << 16);
                *(uint2*)(vp + j * 16) = pk;
            }
        }
    }
}

// ---------- GEMM3: out[z] = qs[z] @ WopT[z]^T + bo (fp32 store) ----------
__global__ __launch_bounds__(512, 2) void gemm_out(
    const u16* __restrict__ A, const u16* __restrict__ BT,
    const float* __restrict__ bias, float* __restrict__ C)
{
    __shared__ u16 As0[2][128 * 64], As1[2][128 * 64];
    __shared__ u16 Bs0[2][128 * 64], Bs1[2][128 * 64];
    const int t = threadIdx.x;
    const int l = t & 63, w = t >> 6;
    const int quad = l >> 4, lrow = l & 15;
    const int wrow = w >> 2, wcol = w & 3;
    const int bhalf = wcol >> 1, brow = (wcol & 1) * 64;
    const int z = blockIdx.z;
    A  += (size_t)z * (4096 * 1024);
    BT += (size_t)z * (1024 * 1024);
    C  += (size_t)z * (4096 * 1024);

    int bx, by;
    {
        const int id = blockIdx.x + (int)gridDim.x * blockIdx.y;
        const int xcd = id & 7, j = id >> 3;
        const int xs = (int)gridDim.x >> 3;    // 2
        bx = xcd * xs + (j % xs);
        by = j / xs;
    }
    const int m0 = bx * 256, n0 = by * 256;

    const int lr0 = t >> 3;
    const int cg = ((t & 7) ^ (lr0 & 7)) * 8;
    const int ldst = lr0 * 64 + (t & 7) * 8;
    const u16* aS = A  + (size_t)(m0 + lr0) * 1024 + cg;
    const u16* bS = BT + (size_t)(n0 + lr0) * 1024 + cg;

    const int kg0 = (quad ^ (lrow & 7)) << 3;
    f4 acc[8][4] = {};

    STG2(Bs0, bS, 0, 0); STG2(Bs0, bS, 1, 0);
    STG2(As0, aS, 0, 0); STG2(As0, aS, 1, 0);
    STG2(Bs1, bS, 0, 1); STG2(Bs1, bS, 1, 1);
    WAITV(4);
    BAR8();

    for (int kt2 = 0; kt2 < 7; ++kt2) {
        const int kt = kt2 * 2;
        {
            const u16* Ab = As0[wrow];
            const u16* Bb = Bs0[bhalf];
            short8 bf[4][2];
            LOADB();
            PHASE(0, STG2(As1, aS, 0, kt + 1), (void)0);
            PHASE(1, STG2(As1, aS, 1, kt + 1), (void)0);
            PHASE(2, STG2(Bs0, bS, 0, kt + 2), (void)0);
            PHASE(3, STG2(Bs0, bS, 1, kt + 2), WAITV(4));
        }
        {
            const u16* Ab = As1[wrow];
            const u16* Bb = Bs1[bhalf];
            short8 bf[4][2];
            LOADB();
            PHASE(0, STG2(As0, aS, 0, kt + 2), (void)0);
            PHASE(1, STG2(As0, aS, 1, kt + 2), (void)0);
            PHASE(2, STG2(Bs1, bS, 0, kt + 3), (void)0);
            PHASE(3, STG2(Bs1, bS, 1, kt + 3), WAITV(4));
        }
    }
    STG2(As1, aS, 0, 15); STG2(As1, aS, 1, 15);
    WAITV(0);
    BAR8();
    KTILE_NOSYNC(As0, Bs0);   // kt=14
    KTILE_NOSYNC(As1, Bs1);   // kt=15

    // epilogue (swapped layout): float4 coalesced stores
    const int colh = n0 + wcol * 64;
    float4 bs4[4];
#pragma unroll
    for (int j = 0; j < 4; ++j)
        bs4[j] = *(const float4*)&bias[colh + j * 16 + quad * 4];
#pragma unroll
    for (int i = 0; i < 8; ++i) {
        const int m = m0 + wrow * 128 + i * 16 + lrow;
        float* cp = C + (size_t)m * 1024 + colh + quad * 4;
#pragma unroll
        for (int j = 0; j < 4; ++j) {
            float4 o;
            o.x = acc[i][j][0] + bs4[j].x;
            o.y = acc[i][j][1] + bs4[j].y;
            o.z = acc[i][j][2] + bs4[j].z;
            o.w = acc[i][j][3] + bs4[j].w;
            *(float4*)(cp + j * 16) = o;
        }
    }
}

// ---------- ctx partials via MFMA: Mpart[split][g][d][e] = sum_n exp(qs[n,d]) * v[n,e] ----
__global__ __launch_bounds__(256) void ctx_mfma(
    const u16* __restrict__ qs, const u16* __restrict__ vb,
    float* __restrict__ Mpart, float* __restrict__ Zpart)
{
    __shared__ __align__(16) u16 Et[2][64 * 64];
    __shared__ __align__(16) u16 Vt[2][64 * 64];
    const int t = threadIdx.x;
    const int w = t >> 6, l = t & 63;
    const int quad = l >> 4, lrow = l & 15;
    const int g = blockIdx.x;          // b = g>>4, h = g&15
    const int split = blockIdx.y;      // 0..15
    const int b = g >> 4, h = g & 15;

    const int n0 = (l & 31) * 2;       // rows n0, n0+1 within slab
    const int d0 = w * 16 + (l >> 5) * 8;
    const u16* qp = qs + ((size_t)b * 4096 + (size_t)split * 256 + n0) * 1024 + h * 64 + d0;
    const u16* vp = vb + ((size_t)b * 4096 + (size_t)split * 256 + n0) * 1024 + h * 64 + d0;

    f4 acc[4] = {};
    float zacc[8] = {};

    us8 q8a = *(const us8*)qp;
    us8 q8b = *(const us8*)(qp + 1024);
    us8 v8a = *(const us8*)vp;
    us8 v8b = *(const us8*)(vp + 1024);

    for (int slab = 0; slab < 4; ++slab) {
        unsigned epk[8], vpk[8];
#pragma unroll
        for (int j = 0; j < 8; ++j) {
            float ea = __expf(bf2f((u16)q8a[j]));
            float eb = __expf(bf2f((u16)q8b[j]));
            zacc[j] += ea + eb;
            epk[j] = (unsigned)f2bf(ea) | ((unsigned)f2bf(eb) << 16);
            vpk[j] = (unsigned)(u16)v8a[j] | ((unsigned)(u16)v8b[j] << 16);
        }
        if (slab < 3) {                // prefetch next slab (overlaps sync+MFMA below)
            qp += 64 * 1024; vp += 64 * 1024;
            q8a = *(const us8*)qp;  q8b = *(const us8*)(qp + 1024);
            v8a = *(const us8*)vp;  v8b = *(const us8*)(vp + 1024);
        }
        u16* et = Et[slab & 1];
        u16* vt = Vt[slab & 1];
#pragma unroll
        for (int j = 0; j < 8; ++j) {
            const int d = d0 + j;
            const int off = d * 64 + (((n0 >> 3) ^ (d & 7)) << 3) + (n0 & 7);
            *(unsigned*)&et[off] = epk[j];
            *(unsigned*)&vt[off] = vpk[j];
        }
        __syncthreads();
#pragma unroll
        for (int kk = 0; kk < 2; ++kk) {
            const int blk = ((kk * 4 + quad) ^ (lrow & 7)) << 3;
            short8 a = *(const short8*)&et[(w * 16 + lrow) * 64 + blk];
#pragma unroll
            for (int j = 0; j < 4; ++j) {
                short8 bfr = *(const short8*)&vt[(j * 16 + lrow) * 64 + blk];
                acc[j] = __builtin_amdgcn_mfma_f32_16x16x32_bf16(bfr, a, acc[j], 0, 0, 0);
            }
        }
    }

    // Z: butterfly within each 32-lane half (all lanes of a half share d0-range)
#pragma unroll
    for (int j = 0; j < 8; ++j) {
        zacc[j] += __shfl_xor(zacc[j], 1);
        zacc[j] += __shfl_xor(zacc[j], 2);
        zacc[j] += __shfl_xor(zacc[j], 4);
        zacc[j] += __shfl_xor(zacc[j], 8);
        zacc[j] += __shfl_xor(zacc[j], 16);
    }
    if ((l & 31) == 0) {
        float* zp = Zpart + ((size_t)split * 64 + g) * 64 + d0;
#pragma unroll
        for (int j = 0; j < 8; ++j) zp[j] = zacc[j];
    }

    // store acc (swapped layout): d = w*16 + lrow, e = j*16 + quad*4 + r -> float4
    float* mp = Mpart + ((size_t)split * 64 + g) * 4096;
#pragma unroll
    for (int j = 0; j < 4; ++j) {
        float4 o;
        o.x = acc[j][0]; o.y = acc[j][1]; o.z = acc[j][2]; o.w = acc[j][3];
        *(float4*)&mp[(w * 16 + lrow) * 64 + j * 16 + quad * 4] = o;
    }
}

// ---------- reduce partials + normalize: ctx2[g][d][e] = s * sum M / sum Z ----------
__global__ __launch_bounds__(256) void ctx_norm(const float* __restrict__ Mpart,
                                                const float* __restrict__ Zpart,
                                                float* __restrict__ ctx2) {
    const int g = blockIdx.x, t = threadIdx.x;
    __shared__ float rz[64];
    if (t < 64) {
        float zsum = 0.f;
#pragma unroll
        for (int s = 0; s < 16; ++s) zsum += Zpart[((size_t)s * 64 + g) * 64 + t];
        rz[t] = SCALE_S / zsum;
    }
    __syncthreads();
    for (int idx = t; idx < 4096; idx += 256) {
        float m = 0.f;
#pragma unroll
        for (int s = 0; s < 16; ++s) m += Mpart[((size_t)s * 64 + g) * 4096 + idx];
        ctx2[(size_t)g * 4096 + idx] = m * rz[idx >> 6];
    }
}

// ---------- W'T_b[j][h*64+d] = sum_e WoT[j][h*64+e] * ctx2[b,h][d][e] ----------
__global__ __launch_bounds__(256) void woprime(const float* __restrict__ ctx2,
                                               const u16* __restrict__ WoT,
                                               u16* __restrict__ WopT) {
    __shared__ float ctxT[64 * 65];          // [e][d], padded
    __shared__ __align__(16) u16 wo[64 * 64];
    const int t = threadIdx.x;
    const int jt = blockIdx.x, h = blockIdx.y, b = blockIdx.z;
    const int g = b * 16 + h;
    for (int idx = t; idx < 4096; idx += 256) {
        const int d = idx >> 6, e = idx & 63;
        ctxT[e * 65 + d] = ctx2[(size_t)g * 4096 + idx];
    }
    const int j0 = jt * 64;
#pragma unroll
    for (int c = 0; c < 2; ++c) {
        const int ii = c * 256 + t;
        const int j = ii >> 3, c8 = ii & 7;
        *(us8*)&wo[j * 64 + c8 * 8] = *(const us8*)&WoT[(size_t)(j0 + j) * 1024 + h * 64 + c8 * 8];
    }
    __syncthreads();
    const int d = t & 63, w = t >> 6;
    float accj[16] = {};
    for (int eb = 0; eb < 8; ++eb) {
        float c8[8];
#pragma unroll
        for (int e = 0; e < 8; ++e) c8[e] = ctxT[(eb * 8 + e) * 65 + d];
#pragma unroll
        for (int jj = 0; jj < 16; ++jj) {
            us8 w8 = *(const us8*)&wo[(jj * 4 + w) * 64 + eb * 8];   // wave-uniform broadcast
#pragma unroll
            for (int e = 0; e < 8; ++e)
                accj[jj] += bf2f((u16)w8[e]) * c8[e];
        }
    }
#pragma unroll
    for (int jj = 0; jj < 16; ++jj)
        WopT[(size_t)b * 1048576 + (size_t)(j0 + jj * 4 + w) * 1024 + h * 64 + d] = f2bf(accj[jj]);
}

// ---------- launch ----------
extern "C" void kernel_launch(void* const* d_in, const int* in_sizes, int n_in,
                              void* d_out, int out_size, void* d_ws, size_t ws_size,
                              hipStream_t stream)
{
    const float* x  = (const float*)d_in[0];
    const float* Wq = (const float*)d_in[1];
    const float* bq = (const float*)d_in[2];
    // d_in[3]=Wk, d_in[4]=bk : dead code in the reference, skipped
    const float* Wv = (const float*)d_in[5];
    const float* bv = (const float*)d_in[6];
    const float* Wo = (const float*)d_in[7];
    const float* bo = (const float*)d_in[8];
    float* out = (float*)d_out;

    char* ws = (char*)d_ws;
    size_t o = 0;
    auto alloc = [&](size_t bytes) { char* p = ws + o; o = (o + bytes + 255) & ~(size_t)255; return p; };
    u16*   x_bf  = (u16*)  alloc(16384ull * 1024 * 2);   // 32 MB (dead after GEMM1 -> reused as Mpart)
    u16*   WqvT  = (u16*)  alloc(2048ull * 1024 * 2);    //  4 MB
    u16*   WoT   = (u16*)  alloc(1024ull * 1024 * 2);    //  2 MB
    float* bqv   = (float*)alloc(2048ull * 4);
    u16*   qs    = (u16*)  alloc(16384ull * 1024 * 2);   // 32 MB
    u16*   vbuf  = (u16*)  alloc(16384ull * 1024 * 2);   // 32 MB
    float* Zpart = (float*)alloc(16ull * 64 * 64 * 4);
    float* ctx2  = (float*)alloc(64ull * 4096 * 4);      //  1 MB
    u16*   WopT  = (u16*)  alloc(4ull * 1024 * 1024 * 2);//  8 MB
    float* Mpart = (float*)x_bf;                         // 16 MB alias (x_bf dead by then)
    (void)ws_size; (void)in_sizes; (void)n_in; (void)out_size;

    convert_f32_bf16<<<8192, 256, 0, stream>>>(x, x_bf);
    transpose_convert3<<<dim3(32, 32, 3), dim3(32, 8), 0, stream>>>(Wq, Wv, Wo, WqvT, WoT);
    concat_bias<<<8, 256, 0, stream>>>(bq, bv, bqv);

    // QV projection + fused first softmax epilogue (256x256 8-phase, static dbuf)
    gemm_qv<<<dim3(64, 8), 512, 0, stream>>>(x_bf, WqvT, bqv, qs, vbuf);
    // second softmax (over seq) folded into MFMA-based weighted-sum partials
    ctx_mfma<<<dim3(64, 16), 256, 0, stream>>>(qs, vbuf, Mpart, Zpart);
    ctx_norm<<<64, 256, 0, stream>>>(Mpart, Zpart, ctx2);
    // W'_b = blockdiag(ctx2_b) @ Wo
    woprime<<<dim3(16, 16, 4), 256, 0, stream>>>(ctx2, WoT, WopT);
    // out = qs @ W'_b + bo (256x256 8-phase, static dbuf)
    gemm_out<<<dim3(16, 4, 4), 512, 0, stream>>>(qs, WopT, bo, out);
}